// Round 5
// baseline (220.056 us; speedup 1.0000x reference)
//
#include <hip/hip_runtime.h>
#include <hip/hip_bf16.h>

#define L_TOT (1 << 18)       // 262144 positions
#define L_SHIFT 18
#define NHEAD 8
#define DHEAD 16
#define DMODEL 128
#define EPSF 1e-6f

typedef float f32x4 __attribute__((ext_vector_type(4)));
typedef short bf16x8 __attribute__((ext_vector_type(8)));

__device__ __forceinline__ float frcp(float x) { return __builtin_amdgcn_rcpf(x); }
__device__ __forceinline__ float sigm(float x) { return frcp(1.0f + __expf(-x)); }
__device__ __forceinline__ unsigned short f2bf(float f) {
    return (unsigned short)((__float_as_uint(f) + 0x8000u) >> 16);
}

// sum across each aligned 4-lane quad (lanes s=0..3 share one l), bcast to all 4
__device__ __forceinline__ float qsum(float x) {
    x += __int_as_float(__builtin_amdgcn_update_dpp(0, __float_as_int(x), 0xB1, 0xf, 0xf, true)); // xor1
    x += __int_as_float(__builtin_amdgcn_update_dpp(0, __float_as_int(x), 0x4E, 0xf, 0xf, true)); // xor2
    return x;
}

// ---------------------------------------------------------------------------
// K1: per-position stats. Block = 256 thr, 64 l's. Staging: coalesced loads,
// sigmoid, bf16-pack (q|k) into swizzled sp[64 l][128 p]. Compute: quad-per-l,
// lane s owns d in {4s..4s+3} for all 8 heads, held in 32 packed registers.
// Cross-lane reductions = 2 DPP quad_perm adds only.
// NOTE: no min-waves clause — VGPR must stay un-capped (spills + graph replay
// was the prime suspect in the round-4 post-timing divergence).
// ---------------------------------------------------------------------------
__global__ __launch_bounds__(256) void k1_stats(
        const float* __restrict__ Q, const float* __restrict__ K,
        float* __restrict__ scale_o, float* __restrict__ wbuf,
        float* __restrict__ sep) {
    __shared__ unsigned int sp[64][128];   // 32 KB
    __shared__ float wlds[8][64];
    __shared__ float slds[8][64];

    const int t = threadIdx.x;
    const int l0 = blockIdx.x * 64;

    // ---- staging: thread owns column cS, loads 32 p-rows of Q and K ----
    {
        const int cS = t & 63;
        const int w = t >> 6;
        const int swS = (cS & 31) << 2;
#pragma unroll
        for (int i = 0; i < 8; ++i) {
            const int pb = 4 * (w + 4 * i);    // 4-row group
            unsigned pk[4];
#pragma unroll
            for (int r = 0; r < 4; ++r) {
                float qv = sigm(Q[((pb + r) << L_SHIFT) + l0 + cS]);
                float kv = sigm(K[((pb + r) << L_SHIFT) + l0 + cS]);
                unsigned qu = __float_as_uint(qv) + 0x8000u;
                unsigned ku = __float_as_uint(kv) + 0x8000u;
                pk[r] = (ku & 0xffff0000u) | (qu >> 16);
            }
            *(uint4*)(&sp[cS][pb ^ swS]) = make_uint4(pk[0], pk[1], pk[2], pk[3]);
        }
    }
    __syncthreads();

    // ---- compute: l = l0 + (t>>2), d-slice s = t&3 ----
    const int c = t >> 2;
    const int s = t & 3;
    const int sw = (c & 31) << 2;

    unsigned a[32];                         // sigma(q)|sigma(k) packed, [h*4+j]
#pragma unroll
    for (int h = 0; h < 8; ++h) {
        const uint4 v = *(const uint4*)&sp[c][(h * 16 + s * 4) ^ sw];
        a[h * 4 + 0] = v.x; a[h * 4 + 1] = v.y;
        a[h * 4 + 2] = v.z; a[h * 4 + 3] = v.w;
    }

    // head sums ks[d], qs[d] over h (in-register, this lane's 4 d's)
    float ks[4] = {0.f, 0.f, 0.f, 0.f}, qs[4] = {0.f, 0.f, 0.f, 0.f};
#pragma unroll
    for (int h = 0; h < 8; ++h)
#pragma unroll
        for (int j = 0; j < 4; ++j) {
            const unsigned u = a[h * 4 + j];
            qs[j] += __uint_as_float(u << 16);
            ks[j] += __uint_as_float(u & 0xffff0000u);
        }

    float kse[4], qse[4];
#pragma unroll
    for (int j = 0; j < 4; ++j) { kse[j] = ks[j] + EPSF; qse[j] = qs[j] + EPSF; }

    // si[h] = 1/sum_d (sq+e)(ks+e);  so[h] = 1/sum_d (sk+e)(qs+e)
    float si[8], so[8];
#pragma unroll
    for (int h = 0; h < 8; ++h) {
        float aq = 0.f, ak = 0.f;
#pragma unroll
        for (int j = 0; j < 4; ++j) {
            const unsigned u = a[h * 4 + j];
            aq += (__uint_as_float(u << 16) + EPSF) * kse[j];
            ak += (__uint_as_float(u & 0xffff0000u) + EPSF) * qse[j];
        }
        si[h] = frcp(qsum(aq));
        so[h] = frcp(qsum(ak));
    }

    // kso[d] = sum_h sk*so[h];  qsi[d] = sum_h sq*si[h]
    float kso[4] = {0.f, 0.f, 0.f, 0.f}, qsi[4] = {0.f, 0.f, 0.f, 0.f};
#pragma unroll
    for (int h = 0; h < 8; ++h)
#pragma unroll
        for (int j = 0; j < 4; ++j) {
            const unsigned u = a[h * 4 + j];
            kso[j] += __uint_as_float(u & 0xffff0000u) * so[h];
            qsi[j] += __uint_as_float(u << 16) * si[h];
        }
#pragma unroll
    for (int j = 0; j < 4; ++j) { kse[j] = kso[j] + EPSF; qse[j] = qsi[j] + EPSF; }

    // conserved sink/source; lane s finalizes h = 2s, 2s+1
    float e2[2], sc2[2];
#pragma unroll
    for (int h = 0; h < 8; ++h) {
        float aq = 0.f, ak = 0.f;
#pragma unroll
        for (int j = 0; j < 4; ++j) {
            const unsigned u = a[h * 4 + j];
            aq += (__uint_as_float(u << 16) + EPSF) * kse[j];
            ak += (__uint_as_float(u & 0xffff0000u) + EPSF) * qse[j];
        }
        const float ck = qsum(aq);
        float cs = qsum(ak);
        if ((h >> 1) == s) {
            cs = fminf(fmaxf(cs, -1.f), 1.f);
            e2[h & 1] = __expf(cs);
            sc2[h & 1] = sigm(ck) * si[h];
        }
    }
    wlds[2 * s + 0][c] = e2[0];
    wlds[2 * s + 1][c] = e2[1];
    slds[2 * s + 0][c] = sc2[0];
    slds[2 * s + 1][c] = sc2[1];
    __syncthreads();

    // ---- per-head block sumexp partials (h = t>>5, 32 threads each) ----
    {
        float v = wlds[t >> 5][t & 31] + wlds[t >> 5][32 + (t & 31)];
        v += __shfl_xor(v, 16, 64);
        v += __shfl_xor(v, 8, 64);
        v += __shfl_xor(v, 4, 64);
        v += __shfl_xor(v, 2, 64);
        v += __shfl_xor(v, 1, 64);
        if ((t & 31) == 0) sep[blockIdx.x * 8 + (t >> 5)] = v;
    }

    // ---- coalesced outputs ----
#pragma unroll
    for (int i = 0; i < 2; ++i) {
        const int idx = t + i * 256;       // 0..511
        const int h = idx >> 6, cc = idx & 63;
        wbuf[(h << L_SHIFT) + l0 + cc] = wlds[h][cc];
        scale_o[(h << L_SHIFT) + l0 + cc] = slds[h][cc];
    }
}

// ---------------------------------------------------------------------------
// K2: partial kv. grid = 8 heads * 64 blocks; block owns 4096 l's;
// thread owns (d,m); DETERMINISTIC: writes parts[b*256+t], no atomics.
// ---------------------------------------------------------------------------
__global__ __launch_bounds__(256) void k2_kv(
        const float* __restrict__ Kg, const float* __restrict__ Vg,
        const float* __restrict__ wg, float* __restrict__ parts) {
    const int b = blockIdx.x;
    const int h = b >> 6;
    const int blk = b & 63;
    const int t = threadIdx.x;
    const int dd = t >> 4, m = t & 15;

    __shared__ float A[16][132];
    __shared__ float Vv[16][132];
    __shared__ float wl[128];

    const int baseK = (h * DHEAD) << L_SHIFT;
    float acc = 0.f;

    for (int ch = 0; ch < 32; ++ch) {
        const int l0 = blk * 4096 + ch * 128;
        __syncthreads();                       // readers done with prev tile
        if (t < 128) wl[t] = wg[(h << L_SHIFT) + l0 + t];
        __syncthreads();                       // wl visible
#pragma unroll
        for (int i = 0; i < 2; ++i) {
            const int e = t + i * 256;         // 0..511
            const int r = e >> 5, c4 = e & 31;
            const float4 kq = *(const float4*)&Kg[baseK + (r << L_SHIFT) + l0 + c4 * 4];
            const float4 vq = *(const float4*)&Vg[baseK + (r << L_SHIFT) + l0 + c4 * 4];
            A[r][c4 * 4 + 0] = sigm(kq.x) * wl[c4 * 4 + 0];
            A[r][c4 * 4 + 1] = sigm(kq.y) * wl[c4 * 4 + 1];
            A[r][c4 * 4 + 2] = sigm(kq.z) * wl[c4 * 4 + 2];
            A[r][c4 * 4 + 3] = sigm(kq.w) * wl[c4 * 4 + 3];
            *(float4*)&Vv[r][c4 * 4] = vq;
        }
        __syncthreads();                       // tile ready
#pragma unroll
        for (int c4 = 0; c4 < 32; ++c4) {
            const float4 av = *(const float4*)&A[dd][c4 * 4];
            const float4 vv = *(const float4*)&Vv[m][c4 * 4];
            acc += av.x * vv.x + av.y * vv.y + av.z * vv.z + av.w * vv.w;
        }
    }
    parts[b * 256 + t] = acc;
}

// ---------------------------------------------------------------------------
// K3: reduce sep -> sumexp; reduce parts -> kv (fixed order, deterministic);
// emit Wkv as bf16-packed pairs wkvb[dim][p/2]. 8 blocks x 256 threads.
// ---------------------------------------------------------------------------
__global__ __launch_bounds__(256) void k3_wkv(
        const float* __restrict__ Wg, const float* __restrict__ parts,
        const float* __restrict__ sep, unsigned* __restrict__ wkvb) {
    const int hb = blockIdx.x;
    const int t = threadIdx.x;
    __shared__ float kvf[256];
    __shared__ float redl[4];

    float p = 0.f;
#pragma unroll
    for (int i = 0; i < 16; ++i) p += sep[(t + i * 256) * 8 + hb];
#pragma unroll
    for (int o = 32; o >= 1; o >>= 1) p += __shfl_xor(p, o, 64);
    if ((t & 63) == 0) redl[t >> 6] = p;

    float kacc = 0.f;
    for (int j = 0; j < 64; ++j)
        kacc += parts[(hb * 64 + j) * 256 + t];

    __syncthreads();
    const float s = (float)L_TOT / (redl[0] + redl[1] + redl[2] + redl[3]);
    kvf[t] = kacc * s;
    __syncthreads();

#pragma unroll
    for (int i = 0; i < 4; ++i) {
        const int j = t + i * 256;              // 0..1023
        const int dim = j & 127, prp = j >> 7;  // prp: 0..7 (pr pairs)
        float a0 = 0.f, a1 = 0.f;
#pragma unroll
        for (int mm = 0; mm < 16; ++mm) {
            const float wv = Wg[dim * 128 + hb * 16 + mm];
            a0 += wv * kvf[(2 * prp) * 16 + mm];
            a1 += wv * kvf[(2 * prp + 1) * 16 + mm];
        }
        wkvb[dim * 64 + hb * 8 + prp] = ((unsigned)f2bf(a1) << 16) | f2bf(a0);
    }
}

// ---------------------------------------------------------------------------
// K4 (MFMA): out[dim,l] = b[dim] + sum_p Wkv[dim][p] * g[p][l]
// ---------------------------------------------------------------------------
__global__ __launch_bounds__(256) void k4_mfma(
        const float* __restrict__ Q, const float* __restrict__ scale_g,
        const unsigned* __restrict__ wkvb, const float* __restrict__ bg,
        float* __restrict__ out) {
    __shared__ unsigned A_lds[128 * 68];     // 34.8 KB
    __shared__ float bias[128];
    const int t = threadIdx.x;

    // stage packed Wkv into LDS
#pragma unroll
    for (int i = 0; i < 8; ++i) {
        const int idx4 = t + i * 256;        // 0..2047 uint4's
        const uint4 v = ((const uint4*)wkvb)[idx4];
        const int row = idx4 >> 4, c4 = idx4 & 15;
        *(uint4*)&A_lds[row * 68 + c4 * 4] = v;
    }
    if (t < 128) bias[t] = bg[t];
    __syncthreads();

    const int w = t >> 6, lane = t & 63;
    const int lq = lane & 15, lh = lane >> 4;

#pragma unroll
    for (int ci = 0; ci < 2; ++ci) {
        const int l = blockIdx.x * 128 + ci * 64 + w * 16 + lq;

        // load Q + scale for all 4 K-steps
        float qv[4][8];
        float scv[4];
#pragma unroll
        for (int ks = 0; ks < 4; ++ks) {
            scv[ks] = scale_g[((ks * 2 + (lane >> 5)) << L_SHIFT) + l];
#pragma unroll
            for (int j = 0; j < 8; ++j) {
                const int p = ks * 32 + lh * 8 + j;
                qv[ks][j] = Q[(p << L_SHIFT) + l];
            }
        }
        bf16x8 bfr[4];
#pragma unroll
        for (int ks = 0; ks < 4; ++ks)
#pragma unroll
            for (int j = 0; j < 8; ++j)
                bfr[ks][j] = (short)f2bf(sigm(qv[ks][j]) * scv[ks]);

        f32x4 acc[8];
#pragma unroll
        for (int mt = 0; mt < 8; ++mt)
            acc[mt] = *(const f32x4*)&bias[mt * 16 + lh * 4];

#pragma unroll
        for (int ks = 0; ks < 4; ++ks) {
#pragma unroll
            for (int mt = 0; mt < 8; ++mt) {
                const int row = mt * 16 + lq;
                const bf16x8 aA = *(const bf16x8*)&A_lds[row * 68 + ks * 16 + lh * 4];
                acc[mt] = __builtin_amdgcn_mfma_f32_16x16x32_bf16(aA, bfr[ks], acc[mt], 0, 0, 0);
            }
        }

#pragma unroll
        for (int mt = 0; mt < 8; ++mt) {
#pragma unroll
            for (int r = 0; r < 4; ++r) {
                const int dim = mt * 16 + lh * 4 + r;
                out[(dim << L_SHIFT) + l] = acc[mt][r];
            }
        }
    }
}

// ---------------------------------------------------------------------------
extern "C" void kernel_launch(void* const* d_in, const int* in_sizes, int n_in,
                              void* d_out, int out_size, void* d_ws, size_t ws_size,
                              hipStream_t stream) {
    const float* Q = (const float*)d_in[0];
    const float* K = (const float*)d_in[1];
    const float* V = (const float*)d_in[2];
    const float* W = (const float*)d_in[3];
    const float* B = (const float*)d_in[4];
    float* out = (float*)d_out;
    float* ws = (float*)d_ws;

    // workspace layout (floats) — every region written before read each call
    float* parts    = ws;                        // 512*256 = 131072
    unsigned* wkvb  = (unsigned*)(ws + 131072);  // 8192 u32
    float* sep      = ws + 139264;               // 4096*8 = 32768
    float* scale    = ws + 172032;               // 8*L
    float* wbuf     = scale + 8 * L_TOT;         // 8*L

    k1_stats<<<L_TOT / 64, 256, 0, stream>>>(Q, K, scale, wbuf, sep);
    k2_kv<<<NHEAD * 64, 256, 0, stream>>>(K, V, wbuf, parts);
    k3_wkv<<<NHEAD, 256, 0, stream>>>(W, parts, sep, wkvb);
    k4_mfma<<<L_TOT / 128, 256, 0, stream>>>(Q, scale, wkvb, B, out);
}